// Round 15
// baseline (276.934 us; speedup 1.0000x reference)
//
#include <hip/hip_runtime.h>
#include <hip/hip_fp16.h>
#include <math.h>

#define N_NODES 100000
#define N_EDGES 3200000
#define N_TOT   (N_EDGES + N_NODES)
#define F_IN    512
#define HID     16
#define NCLS    32
#define NEG_SLOPE 0.2f

#define BSH   7                       // bucket shift: 128 nodes per bucket
#define NBKT  ((N_NODES + 127) / 128) // 782
#define SRC_MASK 0x1FFFF              // 17 bits, N_NODES < 131072

#define G_GROUPS 512
#define EPG (N_EDGES / G_GROUPS)      // 6250 exact (even)
#define NGEMM ((N_NODES + 127) / 128) // 782 gemm blocks

typedef __attribute__((ext_vector_type(4))) _Float16 h4_t;  // 8B fp16 quad
typedef __attribute__((ext_vector_type(8))) _Float16 h8_t;  // 16B fp16 oct

// ---------- in-block edge-dtype detection (int64 vs int32) ----------
__device__ __forceinline__ int detect_fl(const int* __restrict__ ei,
                                         int t, int* sflag) {
  if (t < 64) {
    int v = ei[2 * t + 1];
    unsigned long long m = __ballot(v != 0);
    if (t == 0) *sflag = (m == 0ull) ? 1 : 0;  // 1 => int64 layout
  }
  __syncthreads();
  return *sflag;
}

// ---------- hybrid: gemm1 (782 blocks) + hist (512) + prep (1) ----------
__global__ __launch_bounds__(512) void k_g1h(const float* __restrict__ x,
                                             const float* __restrict__ W,
                                             const float* __restrict__ atts,
                                             const float* __restrict__ attd,
                                             const int* __restrict__ ei,
                                             int* __restrict__ H,
                                             const float* __restrict__ W2,
                                             const float* __restrict__ as2w,
                                             const float* __restrict__ ad2w,
                                             float* __restrict__ ws2,
                                             float* __restrict__ wd2,
                                             _Float16* __restrict__ h,
                                             float* __restrict__ as_,
                                             float* __restrict__ ad_) {
  __shared__ float smem[2 * 128 * 36];   // 36.9KB, reinterpreted per role
  int bid = blockIdx.x;
  int t = threadIdx.x;

  if (bid >= NGEMM) {
    if (bid < NGEMM + G_GROUPS) {
      // ---- hist role ----
      int* hh = (int*)smem;
      int* sflag = hh + NBKT;
      for (int i = t; i < NBKT; i += 512) hh[i] = 0;
      int fl = detect_fl(ei, t, sflag);   // barrier covers hh init
      int g = bid - NGEMM;
      int e0 = g * EPG, e1 = e0 + EPG;
      for (int e = e0 + t; e < e1; e += 512) {
        int d = fl ? ei[2 * (N_EDGES + e)] : ei[N_EDGES + e];
        d = min(max(d, 0), N_NODES - 1);
        atomicAdd(&hh[d >> BSH], 1);
      }
      __syncthreads();
      int* Hrow = H + (size_t)g * NBKT;
      for (int i = t; i < NBKT; i += 512) Hrow[i] = hh[i];
    } else {
      // ---- prep role ----
      if (t < HID) {
        float s = 0.f, d = 0.f;
        for (int c = 0; c < NCLS; ++c) {
          float wv = W2[t * NCLS + c];
          s += wv * as2w[c];
          d += wv * ad2w[c];
        }
        ws2[t] = s;
        wd2[t] = d;
      }
    }
    return;
  }

  // ---- gemm role: async-STAGE split double-buffer, scalar-path W ----
  float (*xs)[128][36] = (float (*)[128][36])smem;
  float* pacc = smem;                  // reused as [4][128][17] after compute
  int wid = t >> 6;
  int lane = t & 63;
  int rhalf = wid & 1;
  int kq = __builtin_amdgcn_readfirstlane(wid >> 1);  // SGPR -> s_load path
  int row = rhalf * 64 + lane;
  int r0 = bid * 128;

  int sr = t >> 3;
  int sk4 = t & 7;
  int sr2 = (t + 512) >> 3;
  int sk42 = (t + 512) & 7;
  const float* xp1 = x + (size_t)min(r0 + sr, N_NODES - 1) * F_IN + sk4 * 4;
  const float* xp2 = x + (size_t)min(r0 + sr2, N_NODES - 1) * F_IN + sk42 * 4;

  float acc[HID];
#pragma unroll
  for (int f = 0; f < HID; ++f) acc[f] = 0.f;

  float4 a0, a1, b0, b1;
  a0 = *(const float4*)(xp1 + 0 * 32);
  a1 = *(const float4*)(xp2 + 0 * 32);
  *(float4*)(&xs[0][sr][sk4 * 4]) = a0;
  *(float4*)(&xs[0][sr2][sk42 * 4]) = a1;
  a0 = *(const float4*)(xp1 + 1 * 32);
  a1 = *(const float4*)(xp2 + 1 * 32);
  __syncthreads();

#pragma unroll
  for (int cc = 0; cc < 8; ++cc) {
    const int c = 2 * cc;
    if (cc < 7) {
      b0 = *(const float4*)(xp1 + (c + 2) * 32);
      b1 = *(const float4*)(xp2 + (c + 2) * 32);
    }
    {
      const float* Wc = W + (c * 32 + kq * 8) * HID;
      float4 xa = *(const float4*)(&xs[0][row][kq * 8 + 0]);
      float4 xb = *(const float4*)(&xs[0][row][kq * 8 + 4]);
#pragma unroll
      for (int f = 0; f < HID; ++f)
        acc[f] += xa.x * Wc[0 * HID + f] + xa.y * Wc[1 * HID + f] +
                  xa.z * Wc[2 * HID + f] + xa.w * Wc[3 * HID + f];
#pragma unroll
      for (int f = 0; f < HID; ++f)
        acc[f] += xb.x * Wc[4 * HID + f] + xb.y * Wc[5 * HID + f] +
                  xb.z * Wc[6 * HID + f] + xb.w * Wc[7 * HID + f];
    }
    *(float4*)(&xs[1][sr][sk4 * 4]) = a0;
    *(float4*)(&xs[1][sr2][sk42 * 4]) = a1;
    __syncthreads();
    if (cc < 7) {
      a0 = *(const float4*)(xp1 + (c + 3) * 32);
      a1 = *(const float4*)(xp2 + (c + 3) * 32);
    }
    {
      const float* Wc = W + ((c + 1) * 32 + kq * 8) * HID;
      float4 xa = *(const float4*)(&xs[1][row][kq * 8 + 0]);
      float4 xb = *(const float4*)(&xs[1][row][kq * 8 + 4]);
#pragma unroll
      for (int f = 0; f < HID; ++f)
        acc[f] += xa.x * Wc[0 * HID + f] + xa.y * Wc[1 * HID + f] +
                  xa.z * Wc[2 * HID + f] + xa.w * Wc[3 * HID + f];
#pragma unroll
      for (int f = 0; f < HID; ++f)
        acc[f] += xb.x * Wc[4 * HID + f] + xb.y * Wc[5 * HID + f] +
                  xb.z * Wc[6 * HID + f] + xb.w * Wc[7 * HID + f];
    }
    if (cc < 7) {
      *(float4*)(&xs[0][sr][sk4 * 4]) = b0;
      *(float4*)(&xs[0][sr2][sk42 * 4]) = b1;
    }
    __syncthreads();
  }

#pragma unroll
  for (int f = 0; f < HID; ++f) pacc[(kq * 128 + row) * 17 + f] = acc[f];
  __syncthreads();

  int rr = t >> 2, g = t & 3;
  float4 s;
  s.x = pacc[(0 * 128 + rr) * 17 + g * 4 + 0] + pacc[(1 * 128 + rr) * 17 + g * 4 + 0] +
        pacc[(2 * 128 + rr) * 17 + g * 4 + 0] + pacc[(3 * 128 + rr) * 17 + g * 4 + 0];
  s.y = pacc[(0 * 128 + rr) * 17 + g * 4 + 1] + pacc[(1 * 128 + rr) * 17 + g * 4 + 1] +
        pacc[(2 * 128 + rr) * 17 + g * 4 + 1] + pacc[(3 * 128 + rr) * 17 + g * 4 + 1];
  s.z = pacc[(0 * 128 + rr) * 17 + g * 4 + 2] + pacc[(1 * 128 + rr) * 17 + g * 4 + 2] +
        pacc[(2 * 128 + rr) * 17 + g * 4 + 2] + pacc[(3 * 128 + rr) * 17 + g * 4 + 2];
  s.w = pacc[(0 * 128 + rr) * 17 + g * 4 + 3] + pacc[(1 * 128 + rr) * 17 + g * 4 + 3] +
        pacc[(2 * 128 + rr) * 17 + g * 4 + 3] + pacc[(3 * 128 + rr) * 17 + g * 4 + 3];
  int orow = r0 + rr;
  if (orow < N_NODES) {
    h4_t hv;
    hv.x = (_Float16)s.x; hv.y = (_Float16)s.y;
    hv.z = (_Float16)s.z; hv.w = (_Float16)s.w;
    *(h4_t*)(h + (size_t)orow * HID + g * 4) = hv;   // fp16 row: 32B, L2-fit
  }

  float4 av = ((const float4*)atts)[g];
  float4 dv = ((const float4*)attd)[g];
  float pas = s.x * av.x + s.y * av.y + s.z * av.z + s.w * av.w;
  float pad = s.x * dv.x + s.y * dv.y + s.z * dv.z + s.w * dv.w;
  pas += __shfl_xor(pas, 1); pas += __shfl_xor(pas, 2);
  pad += __shfl_xor(pad, 1); pad += __shfl_xor(pad, 2);
  if (g == 0 && orow < N_NODES) { as_[orow] = pas; ad_[orow] = pad; }
}

// ---------- phase 2a: per-bucket exclusive scan over groups ----------
__global__ __launch_bounds__(G_GROUPS) void k_colscan(int* __restrict__ H,
                                                      int* __restrict__ tot) {
  __shared__ int s[G_GROUPS];
  int b = blockIdx.x, t = threadIdx.x;
  int v = H[(size_t)t * NBKT + b];
  s[t] = v;
  __syncthreads();
  for (int off = 1; off < G_GROUPS; off <<= 1) {
    int a = (t >= off) ? s[t - off] : 0;
    __syncthreads();
    s[t] += a;
    __syncthreads();
  }
  H[(size_t)t * NBKT + b] = s[t] - v;     // exclusive prefix within bucket
  if (t == G_GROUPS - 1) tot[b] = s[t];   // bucket total
}

// ---------- phase 2b: scan bucket totals ----------
__global__ __launch_bounds__(256) void k_bscan(const int* __restrict__ tot,
                                               int* __restrict__ bbase,
                                               int* __restrict__ cbase,
                                               int* __restrict__ offs) {
  __shared__ int s1[256], s2[256];
  int t = threadIdx.x;
  int c[4], vn[4];
  int sum1 = 0, sum2 = 0;
#pragma unroll
  for (int j = 0; j < 4; ++j) {
    int idx = t * 4 + j;
    int cc = 0, vv = 0;
    if (idx < NBKT) {
      cc = tot[idx];
      int lo = idx << BSH;
      vv = min(128, N_NODES - lo);
    }
    c[j] = cc; vn[j] = vv;
    sum1 += cc; sum2 += cc + vv;
  }
  int o1 = sum1, o2 = sum2;
  s1[t] = sum1; s2[t] = sum2;
  __syncthreads();
  for (int off = 1; off < 256; off <<= 1) {
    int a = 0, b = 0;
    if (t >= off) { a = s1[t - off]; b = s2[t - off]; }
    __syncthreads();
    s1[t] += a; s2[t] += b;
    __syncthreads();
  }
  int r1 = s1[t] - o1;
  int r2 = s2[t] - o2;
#pragma unroll
  for (int j = 0; j < 4; ++j) {
    int idx = t * 4 + j;
    if (idx < NBKT) {
      bbase[idx] = r1; cbase[idx] = r2;
      r1 += c[j];
      r2 += c[j] + vn[j];
    }
  }
  if (t == 0) offs[N_NODES] = N_TOT;
}

// ---------- phase 3: rank-scatter (2-edge vectorized; LDS cursors) ----------
__global__ __launch_bounds__(256) void k_scatter(const int* __restrict__ ei,
                                                 const int* __restrict__ H,
                                                 const int* __restrict__ bbase,
                                                 int* __restrict__ binned) {
  __shared__ int cur[NBKT];
  __shared__ int sflag;
  int g = blockIdx.x, t = threadIdx.x;
  const int* Hrow = H + (size_t)g * NBKT;
  for (int i = t; i < NBKT; i += 256) cur[i] = bbase[i] + Hrow[i];
  int fl = detect_fl(ei, t, &sflag);   // barrier covers cur init
  int e0 = g * EPG, e1 = e0 + EPG;
  if (fl) {
    for (int e = e0 + t * 2; e < e1; e += 512) {
      int4 sv = *(const int4*)(ei + 2 * (size_t)e);
      int4 dv = *(const int4*)(ei + 2 * ((size_t)N_EDGES + e));
      int s0 = min(max(sv.x, 0), N_NODES - 1);
      int d0 = min(max(dv.x, 0), N_NODES - 1);
      int s1 = min(max(sv.z, 0), N_NODES - 1);
      int d1 = min(max(dv.z, 0), N_NODES - 1);
      int p0 = atomicAdd(&cur[d0 >> BSH], 1);
      binned[min(max(p0, 0), N_EDGES - 1)] = ((d0 & 127) << 17) | s0;
      int p1 = atomicAdd(&cur[d1 >> BSH], 1);
      binned[min(max(p1, 0), N_EDGES - 1)] = ((d1 & 127) << 17) | s1;
    }
  } else {
    for (int e = e0 + t * 2; e < e1; e += 512) {
      int2 sv = *(const int2*)(ei + e);
      int2 dv = *(const int2*)(ei + (size_t)N_EDGES + e);
      int s0 = min(max(sv.x, 0), N_NODES - 1);
      int d0 = min(max(dv.x, 0), N_NODES - 1);
      int s1 = min(max(sv.y, 0), N_NODES - 1);
      int d1 = min(max(dv.y, 0), N_NODES - 1);
      int p0 = atomicAdd(&cur[d0 >> BSH], 1);
      binned[min(max(p0, 0), N_EDGES - 1)] = ((d0 & 127) << 17) | s0;
      int p1 = atomicAdd(&cur[d1 >> BSH], 1);
      binned[min(max(p1, 0), N_EDGES - 1)] = ((d1 & 127) << 17) | s1;
    }
  }
}

// ---------- per-bucket counting sort in LDS -> CSR offs + srcS ----------
__global__ __launch_bounds__(256) void k_bucket(const int* __restrict__ tot,
                                                const int* __restrict__ bbase,
                                                const int* __restrict__ cbase,
                                                const int* __restrict__ binned,
                                                int* __restrict__ offs,
                                                int* __restrict__ srcS) {
  __shared__ int cnt[128], cur[128], sc[128];
  __shared__ int hdr[3];
  int b = blockIdx.x, t = threadIdx.x;
  if (t == 0) {
    hdr[0] = min(max(tot[b], 0), N_EDGES);
    hdr[1] = min(max(bbase[b], 0), N_EDGES - 1);
    hdr[2] = min(max(cbase[b], 0), N_TOT - 1);
  }
  if (t < 128) cnt[t] = 0;
  __syncthreads();
  int nb = hdr[0], base = hdr[1], cb = hdr[2];

  for (int i = t; i < nb; i += 256) {
    int pk = binned[min(base + i, N_EDGES - 1)];
    atomicAdd(&cnt[(pk >> 17) & 127], 1);
  }
  __syncthreads();

  int node = (b << BSH) + t;
  int myv = 0;
  if (t < 128) myv = (node < N_NODES) ? cnt[t] + 1 : 0;  // +1 self loop
  if (t < 128) sc[t] = myv;
  __syncthreads();
  for (int off = 1; off < 128; off <<= 1) {
    int v = 0;
    if (t < 128 && t >= off) v = sc[t - off];
    __syncthreads();
    if (t < 128) sc[t] += v;
    __syncthreads();
  }
  if (t < 128 && node < N_NODES) {
    int lofs = sc[t] - myv;
    int o = min(cb + lofs, N_TOT - 1);
    offs[node] = o;
    srcS[o] = node;                  // self-loop occupies slot 0
    cur[t] = lofs + 1;
  }
  __syncthreads();

  for (int i = t; i < nb; i += 256) {
    int pk = binned[min(base + i, N_EDGES - 1)];
    int p = atomicAdd(&cur[(pk >> 17) & 127], 1);
    srcS[min(cb + p, N_TOT - 1)] = pk & SRC_MASK;
  }
}

// ---------- fused aggregate: single-sweep softmax+gather, 16B h loads ----
// Wave per node. Lane = (edge-slot lane>>1, feature-half lane&1): each step
// covers 32 edges; each lane loads 16B (8 fp16) of its edge's h row — 2
// L2 requests/edge (same 64B line) vs 4 in the 8B scheme; request-rate is
// the measured agg bottleneck (r14: byte-halving gave only -13us).
// All shuffles full-wave (clamped source, predicated accumulate only).
template <bool LAYER1>
__global__ __launch_bounds__(256) void k_agg(const int* __restrict__ offs,
                                             const int* __restrict__ srcS,
                                             const float* __restrict__ as_,
                                             const float* __restrict__ ad_,
                                             const _Float16* __restrict__ h,
                                             const float* __restrict__ b1,
                                             const float* __restrict__ ws2,
                                             const float* __restrict__ wd2,
                                             const float* __restrict__ W2,
                                             const float* __restrict__ b2,
                                             _Float16* __restrict__ outh,
                                             float* __restrict__ outf,
                                             float* __restrict__ as2,
                                             float* __restrict__ ad2) {
  int node = blockIdx.x * 4 + (threadIdx.x >> 6);
  if (node >= N_NODES) return;
  int lane = threadIdx.x & 63;
  int ehalf = lane >> 1;    // 32 edge slots per step
  int fh = lane & 1;        // feature half (8 fp16 = 16B)
  int beg = offs[node];
  int end = offs[node + 1];
  beg = min(max(beg, 0), N_TOT);
  end = min(max(end, beg), N_TOT);
  float ad = ad_[node];

  float s_lane = 0.f;
  float acc[8];
#pragma unroll
  for (int k = 0; k < 8; ++k) acc[k] = 0.f;

  for (int i0 = beg; i0 < end; i0 += 64) {
    int nb = min(64, end - i0);
    int sn = 0;
    float p = 0.f;
    if (lane < nb) {
      sn = min(max(srcS[i0 + lane], 0), N_NODES - 1);
      float e = as_[sn] + ad;
      e = e > 0.f ? e : NEG_SLOPE * e;
      p = __expf(e);           // no max-shift: |e| <= ~12, exp safe in fp32
    }
    s_lane += p;
    int steps = (nb + 31) >> 5;
    for (int t = 0; t < steps; ++t) {
      int j = ehalf + 32 * t;
      int jj = min(j, nb - 1);           // clamp so source lane is valid
      float pj = __shfl(p, jj);          // full wave active
      int snj = __shfl(sn, jj);
      if (j < nb) {
        h8_t v = *(const h8_t*)(h + (size_t)snj * HID + fh * 8);
#pragma unroll
        for (int k = 0; k < 8; ++k) acc[k] += pj * (float)v[k];
      }
    }
  }
  // denom across all 64 lanes
#pragma unroll
  for (int off = 1; off < 64; off <<= 1) s_lane += __shfl_xor(s_lane, off);
  // acc across the 32 edge slots (xor offsets 2..32 preserve the fh bit)
#pragma unroll
  for (int off = 2; off < 64; off <<= 1) {
#pragma unroll
    for (int k = 0; k < 8; ++k) acc[k] += __shfl_xor(acc[k], off);
  }
  float inv_s = 1.f / s_lane;

  if (LAYER1) {
    float val[8];
#pragma unroll
    for (int k = 0; k < 8; ++k)
      val[k] = fmaxf(acc[k] * inv_s + b1[fh * 8 + k], 0.f);
    if (lane < 2) {
      h8_t hv;
#pragma unroll
      for (int k = 0; k < 8; ++k) hv[k] = (_Float16)val[k];
      *(h8_t*)(outh + (size_t)node * HID + lane * 8) = hv;
    }
    // fused layer-2 scores from fp32 values (no extra rounding)
    float rs = 0.f, rd = 0.f;
#pragma unroll
    for (int k = 0; k < 8; ++k) {
      rs += val[k] * ws2[fh * 8 + k];
      rd += val[k] * wd2[fh * 8 + k];
    }
    rs += __shfl_xor(rs, 1);
    rd += __shfl_xor(rd, 1);
    if (lane == 0) { as2[node] = rs; ad2[node] = rd; }
  } else {
    // fused k_out: broadcast the 16-dim aggregate from the even/odd lane of
    // each pair (full-wave shuffles, sources always valid), per-lane logit,
    // 32-lane-group log_softmax.
    float hv[HID];
#pragma unroll
    for (int k = 0; k < 8; ++k) {
      hv[k]     = __shfl(acc[k], lane & ~1) * inv_s;
      hv[8 + k] = __shfl(acc[k], (lane & ~1) | 1) * inv_s;
    }
    int c = lane & 31;
    float logit = b2[c];
#pragma unroll
    for (int k = 0; k < HID; ++k) logit += hv[k] * W2[k * NCLS + c];
    float mx = logit;
#pragma unroll
    for (int off = 1; off < 32; off <<= 1) mx = fmaxf(mx, __shfl_xor(mx, off));
    float ex = __expf(logit - mx);
    float se = ex;
#pragma unroll
    for (int off = 1; off < 32; off <<= 1) se += __shfl_xor(se, off);
    if (lane < 32) outf[(size_t)node * NCLS + c] = logit - mx - __logf(se);
  }
}

extern "C" void kernel_launch(void* const* d_in, const int* in_sizes, int n_in,
                              void* d_out, int out_size, void* d_ws, size_t ws_size,
                              hipStream_t stream) {
  const float* x    = (const float*)d_in[0];
  const int*   ei   = (const int*)d_in[1];
  const float* W1   = (const float*)d_in[2];
  const float* as1w = (const float*)d_in[3];
  const float* ad1w = (const float*)d_in[4];
  const float* b1   = (const float*)d_in[5];
  const float* W2   = (const float*)d_in[6];
  const float* as2w = (const float*)d_in[7];
  const float* ad2w = (const float*)d_in[8];
  const float* b2   = (const float*)d_in[9];
  float* out = (float*)d_out;

  char* w = (char*)d_ws;
  size_t off = 0;
  auto alloc = [&](size_t bytes) -> char* {
    char* p = w + off;
    off += (bytes + 511) & ~(size_t)511;
    return p;
  };
  int*      tot   = (int*)alloc((size_t)NBKT * 4);
  int*      bbase = (int*)alloc((size_t)NBKT * 4);
  int*      cbase = (int*)alloc((size_t)NBKT * 4);
  int*      offs  = (int*)alloc((size_t)(N_NODES + 1) * 4);
  int*      srcS  = (int*)alloc((size_t)N_TOT * 4);
  float*    ws2   = (float*)alloc((size_t)HID * 4);
  float*    wd2   = (float*)alloc((size_t)HID * 4);
  int*      H     = (int*)alloc((size_t)G_GROUPS * NBKT * 4);  // 1.6 MB
  _Float16* h1    = (_Float16*)alloc((size_t)N_NODES * HID * 2);  // 3.2 MB fp16
  float*    as1   = (float*)alloc((size_t)N_NODES * 4);
  float*    ad1   = (float*)alloc((size_t)N_NODES * 4);

  // union: binned (12.8MB, dead after k_bucket) vs {hr, as2, ad2}
  // (written by k_agg<true>, which runs after k_bucket — stream-ordered).
  size_t region_begin = off;
  int* binned = (int*)alloc((size_t)N_EDGES * 4);
  off = region_begin;
  _Float16* hr = (_Float16*)alloc((size_t)N_NODES * HID * 2);    // 3.2 MB fp16
  float*    as2 = (float*)alloc((size_t)N_NODES * 4);
  float*    ad2 = (float*)alloc((size_t)N_NODES * 4);

  k_g1h<<<NGEMM + G_GROUPS + 1, 512, 0, stream>>>(x, W1, as1w, ad1w, ei, H,
                                                  W2, as2w, ad2w, ws2, wd2,
                                                  h1, as1, ad1);
  k_colscan<<<NBKT, G_GROUPS, 0, stream>>>(H, tot);
  k_bscan<<<1, 256, 0, stream>>>(tot, bbase, cbase, offs);
  k_scatter<<<G_GROUPS, 256, 0, stream>>>(ei, H, bbase, binned);
  k_bucket<<<NBKT, 256, 0, stream>>>(tot, bbase, cbase, binned, offs, srcS);
  k_agg<true><<<(N_NODES + 3) / 4, 256, 0, stream>>>(offs, srcS, as1, ad1, h1,
                                                     b1, ws2, wd2, nullptr, nullptr,
                                                     hr, nullptr, as2, ad2);
  k_agg<false><<<(N_NODES + 3) / 4, 256, 0, stream>>>(offs, srcS, as2, ad2, hr,
                                                      nullptr, nullptr, nullptr,
                                                      W2, b2, nullptr, out,
                                                      nullptr, nullptr);
}

// Round 16
// 244.628 us; speedup vs baseline: 1.1321x; 1.1321x over previous
//
#include <hip/hip_runtime.h>
#include <hip/hip_fp16.h>
#include <math.h>

#define N_NODES 100000
#define N_EDGES 3200000
#define N_TOT   (N_EDGES + N_NODES)
#define F_IN    512
#define HID     16
#define NCLS    32
#define NEG_SLOPE 0.2f

#define BSH   7                       // bucket shift: 128 nodes per bucket
#define NBKT  ((N_NODES + 127) / 128) // 782
#define SRC_MASK 0x1FFFF              // 17 bits, N_NODES < 131072

#define G_GROUPS 512
#define EPG (N_EDGES / G_GROUPS)      // 6250 exact (even)
#define NGEMM ((N_NODES + 127) / 128) // 782 gemm blocks

typedef __attribute__((ext_vector_type(4))) _Float16 h4_t;  // 8B fp16 quad

// ---------- in-block edge-dtype detection (int64 vs int32) ----------
__device__ __forceinline__ int detect_fl(const int* __restrict__ ei,
                                         int t, int* sflag) {
  if (t < 64) {
    int v = ei[2 * t + 1];
    unsigned long long m = __ballot(v != 0);
    if (t == 0) *sflag = (m == 0ull) ? 1 : 0;  // 1 => int64 layout
  }
  __syncthreads();
  return *sflag;
}

// ---------- hybrid: gemm1 (782 blocks) + hist (512) + prep (1) ----------
__global__ __launch_bounds__(512) void k_g1h(const float* __restrict__ x,
                                             const float* __restrict__ W,
                                             const float* __restrict__ atts,
                                             const float* __restrict__ attd,
                                             const int* __restrict__ ei,
                                             int* __restrict__ H,
                                             const float* __restrict__ W2,
                                             const float* __restrict__ as2w,
                                             const float* __restrict__ ad2w,
                                             float* __restrict__ ws2,
                                             float* __restrict__ wd2,
                                             _Float16* __restrict__ h,
                                             float* __restrict__ as_,
                                             float* __restrict__ ad_) {
  __shared__ float smem[2 * 128 * 36];   // 36.9KB, reinterpreted per role
  int bid = blockIdx.x;
  int t = threadIdx.x;

  if (bid >= NGEMM) {
    if (bid < NGEMM + G_GROUPS) {
      // ---- hist role (dst reads vectorized 2-per-thread, r13 pattern) ----
      int* hh = (int*)smem;
      int* sflag = hh + NBKT;
      for (int i = t; i < NBKT; i += 512) hh[i] = 0;
      int fl = detect_fl(ei, t, sflag);   // barrier covers hh init
      int g = bid - NGEMM;
      int e0 = g * EPG, e1 = e0 + EPG;    // e0, EPG even -> pair alignment
      if (fl) {
        for (int e = e0 + t * 2; e < e1; e += 1024) {
          int4 dv = *(const int4*)(ei + 2 * ((size_t)N_EDGES + e));
          int d0 = min(max(dv.x, 0), N_NODES - 1);
          int d1 = min(max(dv.z, 0), N_NODES - 1);
          atomicAdd(&hh[d0 >> BSH], 1);
          atomicAdd(&hh[d1 >> BSH], 1);
        }
      } else {
        for (int e = e0 + t * 2; e < e1; e += 1024) {
          int2 dv = *(const int2*)(ei + (size_t)N_EDGES + e);
          int d0 = min(max(dv.x, 0), N_NODES - 1);
          int d1 = min(max(dv.y, 0), N_NODES - 1);
          atomicAdd(&hh[d0 >> BSH], 1);
          atomicAdd(&hh[d1 >> BSH], 1);
        }
      }
      __syncthreads();
      int* Hrow = H + (size_t)g * NBKT;
      for (int i = t; i < NBKT; i += 512) Hrow[i] = hh[i];
    } else {
      // ---- prep role ----
      if (t < HID) {
        float s = 0.f, d = 0.f;
        for (int c = 0; c < NCLS; ++c) {
          float wv = W2[t * NCLS + c];
          s += wv * as2w[c];
          d += wv * ad2w[c];
        }
        ws2[t] = s;
        wd2[t] = d;
      }
    }
    return;
  }

  // ---- gemm role: async-STAGE split double-buffer, scalar-path W ----
  float (*xs)[128][36] = (float (*)[128][36])smem;
  float* pacc = smem;                  // reused as [4][128][17] after compute
  int wid = t >> 6;
  int lane = t & 63;
  int rhalf = wid & 1;
  int kq = __builtin_amdgcn_readfirstlane(wid >> 1);  // SGPR -> s_load path
  int row = rhalf * 64 + lane;
  int r0 = bid * 128;

  int sr = t >> 3;
  int sk4 = t & 7;
  int sr2 = (t + 512) >> 3;
  int sk42 = (t + 512) & 7;
  const float* xp1 = x + (size_t)min(r0 + sr, N_NODES - 1) * F_IN + sk4 * 4;
  const float* xp2 = x + (size_t)min(r0 + sr2, N_NODES - 1) * F_IN + sk42 * 4;

  float acc[HID];
#pragma unroll
  for (int f = 0; f < HID; ++f) acc[f] = 0.f;

  float4 a0, a1, b0, b1;
  a0 = *(const float4*)(xp1 + 0 * 32);
  a1 = *(const float4*)(xp2 + 0 * 32);
  *(float4*)(&xs[0][sr][sk4 * 4]) = a0;
  *(float4*)(&xs[0][sr2][sk42 * 4]) = a1;
  a0 = *(const float4*)(xp1 + 1 * 32);
  a1 = *(const float4*)(xp2 + 1 * 32);
  __syncthreads();

#pragma unroll
  for (int cc = 0; cc < 8; ++cc) {
    const int c = 2 * cc;
    if (cc < 7) {
      b0 = *(const float4*)(xp1 + (c + 2) * 32);
      b1 = *(const float4*)(xp2 + (c + 2) * 32);
    }
    {
      const float* Wc = W + (c * 32 + kq * 8) * HID;
      float4 xa = *(const float4*)(&xs[0][row][kq * 8 + 0]);
      float4 xb = *(const float4*)(&xs[0][row][kq * 8 + 4]);
#pragma unroll
      for (int f = 0; f < HID; ++f)
        acc[f] += xa.x * Wc[0 * HID + f] + xa.y * Wc[1 * HID + f] +
                  xa.z * Wc[2 * HID + f] + xa.w * Wc[3 * HID + f];
#pragma unroll
      for (int f = 0; f < HID; ++f)
        acc[f] += xb.x * Wc[4 * HID + f] + xb.y * Wc[5 * HID + f] +
                  xb.z * Wc[6 * HID + f] + xb.w * Wc[7 * HID + f];
    }
    *(float4*)(&xs[1][sr][sk4 * 4]) = a0;
    *(float4*)(&xs[1][sr2][sk42 * 4]) = a1;
    __syncthreads();
    if (cc < 7) {
      a0 = *(const float4*)(xp1 + (c + 3) * 32);
      a1 = *(const float4*)(xp2 + (c + 3) * 32);
    }
    {
      const float* Wc = W + ((c + 1) * 32 + kq * 8) * HID;
      float4 xa = *(const float4*)(&xs[1][row][kq * 8 + 0]);
      float4 xb = *(const float4*)(&xs[1][row][kq * 8 + 4]);
#pragma unroll
      for (int f = 0; f < HID; ++f)
        acc[f] += xa.x * Wc[0 * HID + f] + xa.y * Wc[1 * HID + f] +
                  xa.z * Wc[2 * HID + f] + xa.w * Wc[3 * HID + f];
#pragma unroll
      for (int f = 0; f < HID; ++f)
        acc[f] += xb.x * Wc[4 * HID + f] + xb.y * Wc[5 * HID + f] +
                  xb.z * Wc[6 * HID + f] + xb.w * Wc[7 * HID + f];
    }
    if (cc < 7) {
      *(float4*)(&xs[0][sr][sk4 * 4]) = b0;
      *(float4*)(&xs[0][sr2][sk42 * 4]) = b1;
    }
    __syncthreads();
  }

#pragma unroll
  for (int f = 0; f < HID; ++f) pacc[(kq * 128 + row) * 17 + f] = acc[f];
  __syncthreads();

  int rr = t >> 2, g = t & 3;
  float4 s;
  s.x = pacc[(0 * 128 + rr) * 17 + g * 4 + 0] + pacc[(1 * 128 + rr) * 17 + g * 4 + 0] +
        pacc[(2 * 128 + rr) * 17 + g * 4 + 0] + pacc[(3 * 128 + rr) * 17 + g * 4 + 0];
  s.y = pacc[(0 * 128 + rr) * 17 + g * 4 + 1] + pacc[(1 * 128 + rr) * 17 + g * 4 + 1] +
        pacc[(2 * 128 + rr) * 17 + g * 4 + 1] + pacc[(3 * 128 + rr) * 17 + g * 4 + 1];
  s.z = pacc[(0 * 128 + rr) * 17 + g * 4 + 2] + pacc[(1 * 128 + rr) * 17 + g * 4 + 2] +
        pacc[(2 * 128 + rr) * 17 + g * 4 + 2] + pacc[(3 * 128 + rr) * 17 + g * 4 + 2];
  s.w = pacc[(0 * 128 + rr) * 17 + g * 4 + 3] + pacc[(1 * 128 + rr) * 17 + g * 4 + 3] +
        pacc[(2 * 128 + rr) * 17 + g * 4 + 3] + pacc[(3 * 128 + rr) * 17 + g * 4 + 3];
  int orow = r0 + rr;
  if (orow < N_NODES) {
    h4_t hv;
    hv.x = (_Float16)s.x; hv.y = (_Float16)s.y;
    hv.z = (_Float16)s.z; hv.w = (_Float16)s.w;
    *(h4_t*)(h + (size_t)orow * HID + g * 4) = hv;   // fp16 row: 32B, L2-fit
  }

  float4 av = ((const float4*)atts)[g];
  float4 dv = ((const float4*)attd)[g];
  float pas = s.x * av.x + s.y * av.y + s.z * av.z + s.w * av.w;
  float pad = s.x * dv.x + s.y * dv.y + s.z * dv.z + s.w * dv.w;
  pas += __shfl_xor(pas, 1); pas += __shfl_xor(pas, 2);
  pad += __shfl_xor(pad, 1); pad += __shfl_xor(pad, 2);
  if (g == 0 && orow < N_NODES) { as_[orow] = pas; ad_[orow] = pad; }
}

// ---------- phase 2a: per-bucket exclusive scan over groups ----------
__global__ __launch_bounds__(G_GROUPS) void k_colscan(int* __restrict__ H,
                                                      int* __restrict__ tot) {
  __shared__ int s[G_GROUPS];
  int b = blockIdx.x, t = threadIdx.x;
  int v = H[(size_t)t * NBKT + b];
  s[t] = v;
  __syncthreads();
  for (int off = 1; off < G_GROUPS; off <<= 1) {
    int a = (t >= off) ? s[t - off] : 0;
    __syncthreads();
    s[t] += a;
    __syncthreads();
  }
  H[(size_t)t * NBKT + b] = s[t] - v;     // exclusive prefix within bucket
  if (t == G_GROUPS - 1) tot[b] = s[t];   // bucket total
}

// ---------- phase 2b: scan bucket totals ----------
__global__ __launch_bounds__(256) void k_bscan(const int* __restrict__ tot,
                                               int* __restrict__ bbase,
                                               int* __restrict__ cbase,
                                               int* __restrict__ offs) {
  __shared__ int s1[256], s2[256];
  int t = threadIdx.x;
  int c[4], vn[4];
  int sum1 = 0, sum2 = 0;
#pragma unroll
  for (int j = 0; j < 4; ++j) {
    int idx = t * 4 + j;
    int cc = 0, vv = 0;
    if (idx < NBKT) {
      cc = tot[idx];
      int lo = idx << BSH;
      vv = min(128, N_NODES - lo);
    }
    c[j] = cc; vn[j] = vv;
    sum1 += cc; sum2 += cc + vv;
  }
  int o1 = sum1, o2 = sum2;
  s1[t] = sum1; s2[t] = sum2;
  __syncthreads();
  for (int off = 1; off < 256; off <<= 1) {
    int a = 0, b = 0;
    if (t >= off) { a = s1[t - off]; b = s2[t - off]; }
    __syncthreads();
    s1[t] += a; s2[t] += b;
    __syncthreads();
  }
  int r1 = s1[t] - o1;
  int r2 = s2[t] - o2;
#pragma unroll
  for (int j = 0; j < 4; ++j) {
    int idx = t * 4 + j;
    if (idx < NBKT) {
      bbase[idx] = r1; cbase[idx] = r2;
      r1 += c[j];
      r2 += c[j] + vn[j];
    }
  }
  if (t == 0) offs[N_NODES] = N_TOT;
}

// ---------- phase 3: rank-scatter (2-edge vectorized; LDS cursors) ----------
__global__ __launch_bounds__(256) void k_scatter(const int* __restrict__ ei,
                                                 const int* __restrict__ H,
                                                 const int* __restrict__ bbase,
                                                 int* __restrict__ binned) {
  __shared__ int cur[NBKT];
  __shared__ int sflag;
  int g = blockIdx.x, t = threadIdx.x;
  const int* Hrow = H + (size_t)g * NBKT;
  for (int i = t; i < NBKT; i += 256) cur[i] = bbase[i] + Hrow[i];
  int fl = detect_fl(ei, t, &sflag);   // barrier covers cur init
  int e0 = g * EPG, e1 = e0 + EPG;
  if (fl) {
    for (int e = e0 + t * 2; e < e1; e += 512) {
      int4 sv = *(const int4*)(ei + 2 * (size_t)e);
      int4 dv = *(const int4*)(ei + 2 * ((size_t)N_EDGES + e));
      int s0 = min(max(sv.x, 0), N_NODES - 1);
      int d0 = min(max(dv.x, 0), N_NODES - 1);
      int s1 = min(max(sv.z, 0), N_NODES - 1);
      int d1 = min(max(dv.z, 0), N_NODES - 1);
      int p0 = atomicAdd(&cur[d0 >> BSH], 1);
      binned[min(max(p0, 0), N_EDGES - 1)] = ((d0 & 127) << 17) | s0;
      int p1 = atomicAdd(&cur[d1 >> BSH], 1);
      binned[min(max(p1, 0), N_EDGES - 1)] = ((d1 & 127) << 17) | s1;
    }
  } else {
    for (int e = e0 + t * 2; e < e1; e += 512) {
      int2 sv = *(const int2*)(ei + e);
      int2 dv = *(const int2*)(ei + (size_t)N_EDGES + e);
      int s0 = min(max(sv.x, 0), N_NODES - 1);
      int d0 = min(max(dv.x, 0), N_NODES - 1);
      int s1 = min(max(sv.y, 0), N_NODES - 1);
      int d1 = min(max(dv.y, 0), N_NODES - 1);
      int p0 = atomicAdd(&cur[d0 >> BSH], 1);
      binned[min(max(p0, 0), N_EDGES - 1)] = ((d0 & 127) << 17) | s0;
      int p1 = atomicAdd(&cur[d1 >> BSH], 1);
      binned[min(max(p1, 0), N_EDGES - 1)] = ((d1 & 127) << 17) | s1;
    }
  }
}

// ---------- per-bucket counting sort in LDS -> CSR offs + srcS ----------
__global__ __launch_bounds__(256) void k_bucket(const int* __restrict__ tot,
                                                const int* __restrict__ bbase,
                                                const int* __restrict__ cbase,
                                                const int* __restrict__ binned,
                                                int* __restrict__ offs,
                                                int* __restrict__ srcS) {
  __shared__ int cnt[128], cur[128], sc[128];
  __shared__ int hdr[3];
  int b = blockIdx.x, t = threadIdx.x;
  if (t == 0) {
    hdr[0] = min(max(tot[b], 0), N_EDGES);
    hdr[1] = min(max(bbase[b], 0), N_EDGES - 1);
    hdr[2] = min(max(cbase[b], 0), N_TOT - 1);
  }
  if (t < 128) cnt[t] = 0;
  __syncthreads();
  int nb = hdr[0], base = hdr[1], cb = hdr[2];

  for (int i = t; i < nb; i += 256) {
    int pk = binned[min(base + i, N_EDGES - 1)];
    atomicAdd(&cnt[(pk >> 17) & 127], 1);
  }
  __syncthreads();

  int node = (b << BSH) + t;
  int myv = 0;
  if (t < 128) myv = (node < N_NODES) ? cnt[t] + 1 : 0;  // +1 self loop
  if (t < 128) sc[t] = myv;
  __syncthreads();
  for (int off = 1; off < 128; off <<= 1) {
    int v = 0;
    if (t < 128 && t >= off) v = sc[t - off];
    __syncthreads();
    if (t < 128) sc[t] += v;
    __syncthreads();
  }
  if (t < 128 && node < N_NODES) {
    int lofs = sc[t] - myv;
    int o = min(cb + lofs, N_TOT - 1);
    offs[node] = o;
    srcS[o] = node;                  // self-loop occupies slot 0
    cur[t] = lofs + 1;
  }
  __syncthreads();

  for (int i = t; i < nb; i += 256) {
    int pk = binned[min(base + i, N_EDGES - 1)];
    int p = atomicAdd(&cur[(pk >> 17) & 127], 1);
    srcS[min(cb + p, N_TOT - 1)] = pk & SRC_MASK;
  }
}

// ---------- fused aggregate: single-sweep softmax+gather, fp16 h rows ----
// Wave per node, 4 lanes/edge (8B each): one 32B line-segment per edge —
// the coalescing sweet spot (r15's 16B/2-lane variant doubled distinct
// lines/instr and regressed). All shuffles full-wave (clamped source,
// predicated accumulate only).
template <bool LAYER1>
__global__ __launch_bounds__(256) void k_agg(const int* __restrict__ offs,
                                             const int* __restrict__ srcS,
                                             const float* __restrict__ as_,
                                             const float* __restrict__ ad_,
                                             const _Float16* __restrict__ h,
                                             const float* __restrict__ b1,
                                             const float* __restrict__ ws2,
                                             const float* __restrict__ wd2,
                                             const float* __restrict__ W2,
                                             const float* __restrict__ b2,
                                             _Float16* __restrict__ outh,
                                             float* __restrict__ outf,
                                             float* __restrict__ as2,
                                             float* __restrict__ ad2) {
  int node = blockIdx.x * 4 + (threadIdx.x >> 6);
  if (node >= N_NODES) return;
  int lane = threadIdx.x & 63;
  int esub = lane >> 2;     // 16 edge slots per step
  int f4 = lane & 3;        // feature quad
  int beg = offs[node];
  int end = offs[node + 1];
  beg = min(max(beg, 0), N_TOT);
  end = min(max(end, beg), N_TOT);
  float ad = ad_[node];

  float s_lane = 0.f;
  float4 acc = make_float4(0.f, 0.f, 0.f, 0.f);
  for (int i0 = beg; i0 < end; i0 += 64) {
    int nb = min(64, end - i0);
    int sn = 0;
    float p = 0.f;
    if (lane < nb) {
      sn = min(max(srcS[i0 + lane], 0), N_NODES - 1);
      float e = as_[sn] + ad;
      e = e > 0.f ? e : NEG_SLOPE * e;
      p = __expf(e);           // no max-shift: |e| <= ~12, exp safe in fp32
    }
    s_lane += p;
    int steps = (nb + 15) >> 4;
    for (int t = 0; t < steps; ++t) {
      int j = esub + 16 * t;
      int jj = min(j, nb - 1);           // clamp so source lane is valid
      float pj = __shfl(p, jj);          // full wave active
      int snj = __shfl(sn, jj);
      if (j < nb) {
        h4_t v = *(const h4_t*)(h + (size_t)snj * HID + f4 * 4);
        acc.x += pj * (float)v.x;
        acc.y += pj * (float)v.y;
        acc.z += pj * (float)v.z;
        acc.w += pj * (float)v.w;
      }
    }
  }
#pragma unroll
  for (int off = 1; off < 64; off <<= 1) s_lane += __shfl_xor(s_lane, off);
#pragma unroll
  for (int off = 4; off < 64; off <<= 1) {
    acc.x += __shfl_xor(acc.x, off);
    acc.y += __shfl_xor(acc.y, off);
    acc.z += __shfl_xor(acc.z, off);
    acc.w += __shfl_xor(acc.w, off);
  }
  float inv_s = 1.f / s_lane;

  if (LAYER1) {
    float4 bv = ((const float4*)b1)[f4];
    float4 val;
    val.x = fmaxf(acc.x * inv_s + bv.x, 0.f);
    val.y = fmaxf(acc.y * inv_s + bv.y, 0.f);
    val.z = fmaxf(acc.z * inv_s + bv.z, 0.f);
    val.w = fmaxf(acc.w * inv_s + bv.w, 0.f);
    if (lane < 4) {
      h4_t hv;
      hv.x = (_Float16)val.x; hv.y = (_Float16)val.y;
      hv.z = (_Float16)val.z; hv.w = (_Float16)val.w;
      *(h4_t*)(outh + (size_t)node * HID + lane * 4) = hv;
    }
    // fused layer-2 scores from fp32 values (no extra rounding)
    float4 w_s = ((const float4*)ws2)[f4];
    float4 w_d = ((const float4*)wd2)[f4];
    float rs = val.x * w_s.x + val.y * w_s.y + val.z * w_s.z + val.w * w_s.w;
    float rd = val.x * w_d.x + val.y * w_d.y + val.z * w_d.z + val.w * w_d.w;
    rs += __shfl_xor(rs, 1); rs += __shfl_xor(rs, 2);
    rd += __shfl_xor(rd, 1); rd += __shfl_xor(rd, 2);
    if (lane == 0) { as2[node] = rs; ad2[node] = rd; }
  } else {
    // fused k_out: broadcast 16-dim aggregate (full-wave shuffles, sources
    // (lane&~3)|j always valid), per-lane logit, 32-lane log_softmax.
    float hv[HID];
#pragma unroll
    for (int j = 0; j < 4; ++j) {
      int srcl = (lane & ~3) | j;
      hv[4 * j + 0] = __shfl(acc.x, srcl) * inv_s;
      hv[4 * j + 1] = __shfl(acc.y, srcl) * inv_s;
      hv[4 * j + 2] = __shfl(acc.z, srcl) * inv_s;
      hv[4 * j + 3] = __shfl(acc.w, srcl) * inv_s;
    }
    int c = lane & 31;
    float logit = b2[c];
#pragma unroll
    for (int k = 0; k < HID; ++k) logit += hv[k] * W2[k * NCLS + c];
    float mx = logit;
#pragma unroll
    for (int off = 1; off < 32; off <<= 1) mx = fmaxf(mx, __shfl_xor(mx, off));
    float ex = __expf(logit - mx);
    float se = ex;
#pragma unroll
    for (int off = 1; off < 32; off <<= 1) se += __shfl_xor(se, off);
    if (lane < 32) outf[(size_t)node * NCLS + c] = logit - mx - __logf(se);
  }
}

extern "C" void kernel_launch(void* const* d_in, const int* in_sizes, int n_in,
                              void* d_out, int out_size, void* d_ws, size_t ws_size,
                              hipStream_t stream) {
  const float* x    = (const float*)d_in[0];
  const int*   ei   = (const int*)d_in[1];
  const float* W1   = (const float*)d_in[2];
  const float* as1w = (const float*)d_in[3];
  const float* ad1w = (const float*)d_in[4];
  const float* b1   = (const float*)d_in[5];
  const float* W2   = (const float*)d_in[6];
  const float* as2w = (const float*)d_in[7];
  const float* ad2w = (const float*)d_in[8];
  const float* b2   = (const float*)d_in[9];
  float* out = (float*)d_out;

  char* w = (char*)d_ws;
  size_t off = 0;
  auto alloc = [&](size_t bytes) -> char* {
    char* p = w + off;
    off += (bytes + 511) & ~(size_t)511;
    return p;
  };
  int*      tot   = (int*)alloc((size_t)NBKT * 4);
  int*      bbase = (int*)alloc((size_t)NBKT * 4);
  int*      cbase = (int*)alloc((size_t)NBKT * 4);
  int*      offs  = (int*)alloc((size_t)(N_NODES + 1) * 4);
  int*      srcS  = (int*)alloc((size_t)N_TOT * 4);
  float*    ws2   = (float*)alloc((size_t)HID * 4);
  float*    wd2   = (float*)alloc((size_t)HID * 4);
  int*      H     = (int*)alloc((size_t)G_GROUPS * NBKT * 4);  // 1.6 MB
  _Float16* h1    = (_Float16*)alloc((size_t)N_NODES * HID * 2);  // 3.2 MB fp16
  float*    as1   = (float*)alloc((size_t)N_NODES * 4);
  float*    ad1   = (float*)alloc((size_t)N_NODES * 4);

  // union: binned (12.8MB, dead after k_bucket) vs {hr, as2, ad2}
  // (written by k_agg<true>, which runs after k_bucket — stream-ordered).
  size_t region_begin = off;
  int* binned = (int*)alloc((size_t)N_EDGES * 4);
  off = region_begin;
  _Float16* hr = (_Float16*)alloc((size_t)N_NODES * HID * 2);    // 3.2 MB fp16
  float*    as2 = (float*)alloc((size_t)N_NODES * 4);
  float*    ad2 = (float*)alloc((size_t)N_NODES * 4);

  k_g1h<<<NGEMM + G_GROUPS + 1, 512, 0, stream>>>(x, W1, as1w, ad1w, ei, H,
                                                  W2, as2w, ad2w, ws2, wd2,
                                                  h1, as1, ad1);
  k_colscan<<<NBKT, G_GROUPS, 0, stream>>>(H, tot);
  k_bscan<<<1, 256, 0, stream>>>(tot, bbase, cbase, offs);
  k_scatter<<<G_GROUPS, 256, 0, stream>>>(ei, H, bbase, binned);
  k_bucket<<<NBKT, 256, 0, stream>>>(tot, bbase, cbase, binned, offs, srcS);
  k_agg<true><<<(N_NODES + 3) / 4, 256, 0, stream>>>(offs, srcS, as1, ad1, h1,
                                                     b1, ws2, wd2, nullptr, nullptr,
                                                     hr, nullptr, as2, ad2);
  k_agg<false><<<(N_NODES + 3) / 4, 256, 0, stream>>>(offs, srcS, as2, ad2, hr,
                                                      nullptr, nullptr, nullptr,
                                                      W2, b2, nullptr, out,
                                                      nullptr, nullptr);
}

// Round 17
// 243.258 us; speedup vs baseline: 1.1384x; 1.0056x over previous
//
#include <hip/hip_runtime.h>
#include <hip/hip_fp16.h>
#include <math.h>

#define N_NODES 100000
#define N_EDGES 3200000
#define N_TOT   (N_EDGES + N_NODES)
#define F_IN    512
#define HID     16
#define NCLS    32
#define NEG_SLOPE 0.2f

#define BSH   7                       // bucket shift: 128 nodes per bucket
#define NBKT  ((N_NODES + 127) / 128) // 782
#define SRC_MASK 0x1FFFF              // 17 bits, N_NODES < 131072

#define G_GROUPS 512
#define EPG (N_EDGES / G_GROUPS)      // 6250 exact (even)
#define NGEMM ((N_NODES + 127) / 128) // 782 gemm blocks

typedef __attribute__((ext_vector_type(4))) _Float16 h4_t;  // 8B fp16 quad

// ---------- in-block edge-dtype detection (int64 vs int32) ----------
__device__ __forceinline__ int detect_fl(const int* __restrict__ ei,
                                         int t, int* sflag) {
  if (t < 64) {
    int v = ei[2 * t + 1];
    unsigned long long m = __ballot(v != 0);
    if (t == 0) *sflag = (m == 0ull) ? 1 : 0;  // 1 => int64 layout
  }
  __syncthreads();
  return *sflag;
}

// ---------- hybrid: gemm1 (782 blocks) + hist (512) + prep (1) ----------
__global__ __launch_bounds__(512) void k_g1h(const float* __restrict__ x,
                                             const float* __restrict__ W,
                                             const float* __restrict__ atts,
                                             const float* __restrict__ attd,
                                             const int* __restrict__ ei,
                                             int* __restrict__ H,
                                             const float* __restrict__ W2,
                                             const float* __restrict__ as2w,
                                             const float* __restrict__ ad2w,
                                             float* __restrict__ ws2,
                                             float* __restrict__ wd2,
                                             _Float16* __restrict__ h,
                                             float* __restrict__ as_,
                                             float* __restrict__ ad_) {
  __shared__ float smem[2 * 128 * 36];   // 36.9KB, reinterpreted per role
  int bid = blockIdx.x;
  int t = threadIdx.x;

  if (bid >= NGEMM) {
    if (bid < NGEMM + G_GROUPS) {
      // ---- hist role (dst reads vectorized 2-per-thread) ----
      int* hh = (int*)smem;
      int* sflag = hh + NBKT;
      for (int i = t; i < NBKT; i += 512) hh[i] = 0;
      int fl = detect_fl(ei, t, sflag);   // barrier covers hh init
      int g = bid - NGEMM;
      int e0 = g * EPG, e1 = e0 + EPG;    // e0, EPG even -> pair alignment
      if (fl) {
        for (int e = e0 + t * 2; e < e1; e += 1024) {
          int4 dv = *(const int4*)(ei + 2 * ((size_t)N_EDGES + e));
          int d0 = min(max(dv.x, 0), N_NODES - 1);
          int d1 = min(max(dv.z, 0), N_NODES - 1);
          atomicAdd(&hh[d0 >> BSH], 1);
          atomicAdd(&hh[d1 >> BSH], 1);
        }
      } else {
        for (int e = e0 + t * 2; e < e1; e += 1024) {
          int2 dv = *(const int2*)(ei + (size_t)N_EDGES + e);
          int d0 = min(max(dv.x, 0), N_NODES - 1);
          int d1 = min(max(dv.y, 0), N_NODES - 1);
          atomicAdd(&hh[d0 >> BSH], 1);
          atomicAdd(&hh[d1 >> BSH], 1);
        }
      }
      __syncthreads();
      int* Hrow = H + (size_t)g * NBKT;
      for (int i = t; i < NBKT; i += 512) Hrow[i] = hh[i];
    } else {
      // ---- prep role ----
      if (t < HID) {
        float s = 0.f, d = 0.f;
        for (int c = 0; c < NCLS; ++c) {
          float wv = W2[t * NCLS + c];
          s += wv * as2w[c];
          d += wv * ad2w[c];
        }
        ws2[t] = s;
        wd2[t] = d;
      }
    }
    return;
  }

  // ---- gemm role: async-STAGE split double-buffer, scalar-path W ----
  float (*xs)[128][36] = (float (*)[128][36])smem;
  float* pacc = smem;                  // reused as [4][128][17] after compute
  int wid = t >> 6;
  int lane = t & 63;
  int rhalf = wid & 1;
  int kq = __builtin_amdgcn_readfirstlane(wid >> 1);  // SGPR -> s_load path
  int row = rhalf * 64 + lane;
  int r0 = bid * 128;

  int sr = t >> 3;
  int sk4 = t & 7;
  int sr2 = (t + 512) >> 3;
  int sk42 = (t + 512) & 7;
  const float* xp1 = x + (size_t)min(r0 + sr, N_NODES - 1) * F_IN + sk4 * 4;
  const float* xp2 = x + (size_t)min(r0 + sr2, N_NODES - 1) * F_IN + sk42 * 4;

  float acc[HID];
#pragma unroll
  for (int f = 0; f < HID; ++f) acc[f] = 0.f;

  float4 a0, a1, b0, b1;
  a0 = *(const float4*)(xp1 + 0 * 32);
  a1 = *(const float4*)(xp2 + 0 * 32);
  *(float4*)(&xs[0][sr][sk4 * 4]) = a0;
  *(float4*)(&xs[0][sr2][sk42 * 4]) = a1;
  a0 = *(const float4*)(xp1 + 1 * 32);
  a1 = *(const float4*)(xp2 + 1 * 32);
  __syncthreads();

#pragma unroll
  for (int cc = 0; cc < 8; ++cc) {
    const int c = 2 * cc;
    if (cc < 7) {
      b0 = *(const float4*)(xp1 + (c + 2) * 32);
      b1 = *(const float4*)(xp2 + (c + 2) * 32);
    }
    {
      const float* Wc = W + (c * 32 + kq * 8) * HID;
      float4 xa = *(const float4*)(&xs[0][row][kq * 8 + 0]);
      float4 xb = *(const float4*)(&xs[0][row][kq * 8 + 4]);
#pragma unroll
      for (int f = 0; f < HID; ++f)
        acc[f] += xa.x * Wc[0 * HID + f] + xa.y * Wc[1 * HID + f] +
                  xa.z * Wc[2 * HID + f] + xa.w * Wc[3 * HID + f];
#pragma unroll
      for (int f = 0; f < HID; ++f)
        acc[f] += xb.x * Wc[4 * HID + f] + xb.y * Wc[5 * HID + f] +
                  xb.z * Wc[6 * HID + f] + xb.w * Wc[7 * HID + f];
    }
    *(float4*)(&xs[1][sr][sk4 * 4]) = a0;
    *(float4*)(&xs[1][sr2][sk42 * 4]) = a1;
    __syncthreads();
    if (cc < 7) {
      a0 = *(const float4*)(xp1 + (c + 3) * 32);
      a1 = *(const float4*)(xp2 + (c + 3) * 32);
    }
    {
      const float* Wc = W + ((c + 1) * 32 + kq * 8) * HID;
      float4 xa = *(const float4*)(&xs[1][row][kq * 8 + 0]);
      float4 xb = *(const float4*)(&xs[1][row][kq * 8 + 4]);
#pragma unroll
      for (int f = 0; f < HID; ++f)
        acc[f] += xa.x * Wc[0 * HID + f] + xa.y * Wc[1 * HID + f] +
                  xa.z * Wc[2 * HID + f] + xa.w * Wc[3 * HID + f];
#pragma unroll
      for (int f = 0; f < HID; ++f)
        acc[f] += xb.x * Wc[4 * HID + f] + xb.y * Wc[5 * HID + f] +
                  xb.z * Wc[6 * HID + f] + xb.w * Wc[7 * HID + f];
    }
    if (cc < 7) {
      *(float4*)(&xs[0][sr][sk4 * 4]) = b0;
      *(float4*)(&xs[0][sr2][sk42 * 4]) = b1;
    }
    __syncthreads();
  }

#pragma unroll
  for (int f = 0; f < HID; ++f) pacc[(kq * 128 + row) * 17 + f] = acc[f];
  __syncthreads();

  int rr = t >> 2, g = t & 3;
  float4 s;
  s.x = pacc[(0 * 128 + rr) * 17 + g * 4 + 0] + pacc[(1 * 128 + rr) * 17 + g * 4 + 0] +
        pacc[(2 * 128 + rr) * 17 + g * 4 + 0] + pacc[(3 * 128 + rr) * 17 + g * 4 + 0];
  s.y = pacc[(0 * 128 + rr) * 17 + g * 4 + 1] + pacc[(1 * 128 + rr) * 17 + g * 4 + 1] +
        pacc[(2 * 128 + rr) * 17 + g * 4 + 1] + pacc[(3 * 128 + rr) * 17 + g * 4 + 1];
  s.z = pacc[(0 * 128 + rr) * 17 + g * 4 + 2] + pacc[(1 * 128 + rr) * 17 + g * 4 + 2] +
        pacc[(2 * 128 + rr) * 17 + g * 4 + 2] + pacc[(3 * 128 + rr) * 17 + g * 4 + 2];
  s.w = pacc[(0 * 128 + rr) * 17 + g * 4 + 3] + pacc[(1 * 128 + rr) * 17 + g * 4 + 3] +
        pacc[(2 * 128 + rr) * 17 + g * 4 + 3] + pacc[(3 * 128 + rr) * 17 + g * 4 + 3];
  int orow = r0 + rr;
  if (orow < N_NODES) {
    h4_t hv;
    hv.x = (_Float16)s.x; hv.y = (_Float16)s.y;
    hv.z = (_Float16)s.z; hv.w = (_Float16)s.w;
    *(h4_t*)(h + (size_t)orow * HID + g * 4) = hv;   // fp16 row: 32B, L2-fit
  }

  float4 av = ((const float4*)atts)[g];
  float4 dv = ((const float4*)attd)[g];
  float pas = s.x * av.x + s.y * av.y + s.z * av.z + s.w * av.w;
  float pad = s.x * dv.x + s.y * dv.y + s.z * dv.z + s.w * dv.w;
  pas += __shfl_xor(pas, 1); pas += __shfl_xor(pas, 2);
  pad += __shfl_xor(pad, 1); pad += __shfl_xor(pad, 2);
  if (g == 0 && orow < N_NODES) { as_[orow] = pas; ad_[orow] = pad; }
}

// ---------- phase 2a: per-bucket exclusive scan over groups ----------
__global__ __launch_bounds__(G_GROUPS) void k_colscan(int* __restrict__ H,
                                                      int* __restrict__ tot) {
  __shared__ int s[G_GROUPS];
  int b = blockIdx.x, t = threadIdx.x;
  int v = H[(size_t)t * NBKT + b];
  s[t] = v;
  __syncthreads();
  for (int off = 1; off < G_GROUPS; off <<= 1) {
    int a = (t >= off) ? s[t - off] : 0;
    __syncthreads();
    s[t] += a;
    __syncthreads();
  }
  H[(size_t)t * NBKT + b] = s[t] - v;     // exclusive prefix within bucket
  if (t == G_GROUPS - 1) tot[b] = s[t];   // bucket total
}

// ---------- phase 2b: scan bucket totals ----------
__global__ __launch_bounds__(256) void k_bscan(const int* __restrict__ tot,
                                               int* __restrict__ bbase,
                                               int* __restrict__ cbase,
                                               int* __restrict__ offs) {
  __shared__ int s1[256], s2[256];
  int t = threadIdx.x;
  int c[4], vn[4];
  int sum1 = 0, sum2 = 0;
#pragma unroll
  for (int j = 0; j < 4; ++j) {
    int idx = t * 4 + j;
    int cc = 0, vv = 0;
    if (idx < NBKT) {
      cc = tot[idx];
      int lo = idx << BSH;
      vv = min(128, N_NODES - lo);
    }
    c[j] = cc; vn[j] = vv;
    sum1 += cc; sum2 += cc + vv;
  }
  int o1 = sum1, o2 = sum2;
  s1[t] = sum1; s2[t] = sum2;
  __syncthreads();
  for (int off = 1; off < 256; off <<= 1) {
    int a = 0, b = 0;
    if (t >= off) { a = s1[t - off]; b = s2[t - off]; }
    __syncthreads();
    s1[t] += a; s2[t] += b;
    __syncthreads();
  }
  int r1 = s1[t] - o1;
  int r2 = s2[t] - o2;
#pragma unroll
  for (int j = 0; j < 4; ++j) {
    int idx = t * 4 + j;
    if (idx < NBKT) {
      bbase[idx] = r1; cbase[idx] = r2;
      r1 += c[j];
      r2 += c[j] + vn[j];
    }
  }
  if (t == 0) offs[N_NODES] = N_TOT;
}

// ---------- phase 3: rank-scatter (2-edge vectorized; LDS cursors) ----------
__global__ __launch_bounds__(256) void k_scatter(const int* __restrict__ ei,
                                                 const int* __restrict__ H,
                                                 const int* __restrict__ bbase,
                                                 int* __restrict__ binned) {
  __shared__ int cur[NBKT];
  __shared__ int sflag;
  int g = blockIdx.x, t = threadIdx.x;
  const int* Hrow = H + (size_t)g * NBKT;
  for (int i = t; i < NBKT; i += 256) cur[i] = bbase[i] + Hrow[i];
  int fl = detect_fl(ei, t, &sflag);   // barrier covers cur init
  int e0 = g * EPG, e1 = e0 + EPG;
  if (fl) {
    for (int e = e0 + t * 2; e < e1; e += 512) {
      int4 sv = *(const int4*)(ei + 2 * (size_t)e);
      int4 dv = *(const int4*)(ei + 2 * ((size_t)N_EDGES + e));
      int s0 = min(max(sv.x, 0), N_NODES - 1);
      int d0 = min(max(dv.x, 0), N_NODES - 1);
      int s1 = min(max(sv.z, 0), N_NODES - 1);
      int d1 = min(max(dv.z, 0), N_NODES - 1);
      int p0 = atomicAdd(&cur[d0 >> BSH], 1);
      binned[min(max(p0, 0), N_EDGES - 1)] = ((d0 & 127) << 17) | s0;
      int p1 = atomicAdd(&cur[d1 >> BSH], 1);
      binned[min(max(p1, 0), N_EDGES - 1)] = ((d1 & 127) << 17) | s1;
    }
  } else {
    for (int e = e0 + t * 2; e < e1; e += 512) {
      int2 sv = *(const int2*)(ei + e);
      int2 dv = *(const int2*)(ei + (size_t)N_EDGES + e);
      int s0 = min(max(sv.x, 0), N_NODES - 1);
      int d0 = min(max(dv.x, 0), N_NODES - 1);
      int s1 = min(max(sv.y, 0), N_NODES - 1);
      int d1 = min(max(dv.y, 0), N_NODES - 1);
      int p0 = atomicAdd(&cur[d0 >> BSH], 1);
      binned[min(max(p0, 0), N_EDGES - 1)] = ((d0 & 127) << 17) | s0;
      int p1 = atomicAdd(&cur[d1 >> BSH], 1);
      binned[min(max(p1, 0), N_EDGES - 1)] = ((d1 & 127) << 17) | s1;
    }
  }
}

// ---------- per-bucket counting sort in LDS -> CSR offs + srcS ----------
// Both passes read binned as aligned int2 pairs (start rounded down to even,
// boundary elements predicated) — halves load instrs over 2x13MB.
__global__ __launch_bounds__(256) void k_bucket(const int* __restrict__ tot,
                                                const int* __restrict__ bbase,
                                                const int* __restrict__ cbase,
                                                const int* __restrict__ binned,
                                                int* __restrict__ offs,
                                                int* __restrict__ srcS) {
  __shared__ int cnt[128], cur[128], sc[128];
  __shared__ int hdr[3];
  int b = blockIdx.x, t = threadIdx.x;
  if (t == 0) {
    hdr[0] = min(max(tot[b], 0), N_EDGES);
    hdr[1] = min(max(bbase[b], 0), N_EDGES - 1);
    hdr[2] = min(max(cbase[b], 0), N_TOT - 1);
  }
  if (t < 128) cnt[t] = 0;
  __syncthreads();
  int nb = hdr[0], base = hdr[1], cb = hdr[2];
  int endb = base + nb;
  int startp = base & ~1;

  for (int idx = startp + t * 2; idx < endb; idx += 512) {
    int2 v = *(const int2*)(binned + min(idx, N_EDGES - 2));
    if (idx >= base)     atomicAdd(&cnt[(v.x >> 17) & 127], 1);
    if (idx + 1 < endb)  atomicAdd(&cnt[(v.y >> 17) & 127], 1);
  }
  __syncthreads();

  int node = (b << BSH) + t;
  int myv = 0;
  if (t < 128) myv = (node < N_NODES) ? cnt[t] + 1 : 0;  // +1 self loop
  if (t < 128) sc[t] = myv;
  __syncthreads();
  for (int off = 1; off < 128; off <<= 1) {
    int v = 0;
    if (t < 128 && t >= off) v = sc[t - off];
    __syncthreads();
    if (t < 128) sc[t] += v;
    __syncthreads();
  }
  if (t < 128 && node < N_NODES) {
    int lofs = sc[t] - myv;
    int o = min(cb + lofs, N_TOT - 1);
    offs[node] = o;
    srcS[o] = node;                  // self-loop occupies slot 0
    cur[t] = lofs + 1;
  }
  __syncthreads();

  for (int idx = startp + t * 2; idx < endb; idx += 512) {
    int2 v = *(const int2*)(binned + min(idx, N_EDGES - 2));
    if (idx >= base) {
      int p2 = atomicAdd(&cur[(v.x >> 17) & 127], 1);
      srcS[min(cb + p2, N_TOT - 1)] = v.x & SRC_MASK;
    }
    if (idx + 1 < endb) {
      int p2 = atomicAdd(&cur[(v.y >> 17) & 127], 1);
      srcS[min(cb + p2, N_TOT - 1)] = v.y & SRC_MASK;
    }
  }
}

// ---------- fused aggregate: single-sweep softmax+gather, fp16 h rows ----
// Wave per node, 4 lanes/edge (8B each, one 32B segment per edge). The
// 16-edge broadcast steps are PEELED: full steps run unguarded (only the
// final step of a chunk can be partial) — identical arithmetic order.
// All shuffles full-wave (clamped source in tail, predicated accumulate).
template <bool LAYER1>
__global__ __launch_bounds__(256) void k_agg(const int* __restrict__ offs,
                                             const int* __restrict__ srcS,
                                             const float* __restrict__ as_,
                                             const float* __restrict__ ad_,
                                             const _Float16* __restrict__ h,
                                             const float* __restrict__ b1,
                                             const float* __restrict__ ws2,
                                             const float* __restrict__ wd2,
                                             const float* __restrict__ W2,
                                             const float* __restrict__ b2,
                                             _Float16* __restrict__ outh,
                                             float* __restrict__ outf,
                                             float* __restrict__ as2,
                                             float* __restrict__ ad2) {
  int node = blockIdx.x * 4 + (threadIdx.x >> 6);
  if (node >= N_NODES) return;
  int lane = threadIdx.x & 63;
  int esub = lane >> 2;     // 16 edge slots per step
  int f4 = lane & 3;        // feature quad
  int beg = offs[node];
  int end = offs[node + 1];
  beg = min(max(beg, 0), N_TOT);
  end = min(max(end, beg), N_TOT);
  float ad = ad_[node];

  float s_lane = 0.f;
  float4 acc = make_float4(0.f, 0.f, 0.f, 0.f);
  for (int i0 = beg; i0 < end; i0 += 64) {
    int nb = min(64, end - i0);
    int sn = 0;
    float p = 0.f;
    if (lane < nb) {
      sn = min(max(srcS[i0 + lane], 0), N_NODES - 1);
      float e = as_[sn] + ad;
      e = e > 0.f ? e : NEG_SLOPE * e;
      p = __expf(e);           // no max-shift: |e| <= ~12, exp safe in fp32
    }
    s_lane += p;
    int full = nb >> 4;                  // full 16-edge steps (j < nb holds)
    for (int t = 0; t < full; ++t) {
      int j = esub + 16 * t;
      float pj = __shfl(p, j);           // full wave active, source valid
      int snj = __shfl(sn, j);
      h4_t v = *(const h4_t*)(h + (size_t)snj * HID + f4 * 4);
      acc.x += pj * (float)v.x;
      acc.y += pj * (float)v.y;
      acc.z += pj * (float)v.z;
      acc.w += pj * (float)v.w;
    }
    if (nb & 15) {                       // partial tail step
      int j = esub + 16 * full;
      int jj = min(j, nb - 1);           // clamp so source lane is valid
      float pj = __shfl(p, jj);          // full wave active
      int snj = __shfl(sn, jj);
      if (j < nb) {
        h4_t v = *(const h4_t*)(h + (size_t)snj * HID + f4 * 4);
        acc.x += pj * (float)v.x;
        acc.y += pj * (float)v.y;
        acc.z += pj * (float)v.z;
        acc.w += pj * (float)v.w;
      }
    }
  }
#pragma unroll
  for (int off = 1; off < 64; off <<= 1) s_lane += __shfl_xor(s_lane, off);
#pragma unroll
  for (int off = 4; off < 64; off <<= 1) {
    acc.x += __shfl_xor(acc.x, off);
    acc.y += __shfl_xor(acc.y, off);
    acc.z += __shfl_xor(acc.z, off);
    acc.w += __shfl_xor(acc.w, off);
  }
  float inv_s = 1.f / s_lane;

  if (LAYER1) {
    float4 bv = ((const float4*)b1)[f4];
    float4 val;
    val.x = fmaxf(acc.x * inv_s + bv.x, 0.f);
    val.y = fmaxf(acc.y * inv_s + bv.y, 0.f);
    val.z = fmaxf(acc.z * inv_s + bv.z, 0.f);
    val.w = fmaxf(acc.w * inv_s + bv.w, 0.f);
    if (lane < 4) {
      h4_t hv;
      hv.x = (_Float16)val.x; hv.y = (_Float16)val.y;
      hv.z = (_Float16)val.z; hv.w = (_Float16)val.w;
      *(h4_t*)(outh + (size_t)node * HID + lane * 4) = hv;
    }
    // fused layer-2 scores from fp32 values (no extra rounding)
    float4 w_s = ((const float4*)ws2)[f4];
    float4 w_d = ((const float4*)wd2)[f4];
    float rs = val.x * w_s.x + val.y * w_s.y + val.z * w_s.z + val.w * w_s.w;
    float rd = val.x * w_d.x + val.y * w_d.y + val.z * w_d.z + val.w * w_d.w;
    rs += __shfl_xor(rs, 1); rs += __shfl_xor(rs, 2);
    rd += __shfl_xor(rd, 1); rd += __shfl_xor(rd, 2);
    if (lane == 0) { as2[node] = rs; ad2[node] = rd; }
  } else {
    // fused k_out: broadcast 16-dim aggregate (full-wave shuffles, sources
    // (lane&~3)|j always valid), per-lane logit, 32-lane log_softmax.
    float hv[HID];
#pragma unroll
    for (int j = 0; j < 4; ++j) {
      int srcl = (lane & ~3) | j;
      hv[4 * j + 0] = __shfl(acc.x, srcl) * inv_s;
      hv[4 * j + 1] = __shfl(acc.y, srcl) * inv_s;
      hv[4 * j + 2] = __shfl(acc.z, srcl) * inv_s;
      hv[4 * j + 3] = __shfl(acc.w, srcl) * inv_s;
    }
    int c = lane & 31;
    float logit = b2[c];
#pragma unroll
    for (int k = 0; k < HID; ++k) logit += hv[k] * W2[k * NCLS + c];
    float mx = logit;
#pragma unroll
    for (int off = 1; off < 32; off <<= 1) mx = fmaxf(mx, __shfl_xor(mx, off));
    float ex = __expf(logit - mx);
    float se = ex;
#pragma unroll
    for (int off = 1; off < 32; off <<= 1) se += __shfl_xor(se, off);
    if (lane < 32) outf[(size_t)node * NCLS + c] = logit - mx - __logf(se);
  }
}

extern "C" void kernel_launch(void* const* d_in, const int* in_sizes, int n_in,
                              void* d_out, int out_size, void* d_ws, size_t ws_size,
                              hipStream_t stream) {
  const float* x    = (const float*)d_in[0];
  const int*   ei   = (const int*)d_in[1];
  const float* W1   = (const float*)d_in[2];
  const float* as1w = (const float*)d_in[3];
  const float* ad1w = (const float*)d_in[4];
  const float* b1   = (const float*)d_in[5];
  const float* W2   = (const float*)d_in[6];
  const float* as2w = (const float*)d_in[7];
  const float* ad2w = (const float*)d_in[8];
  const float* b2   = (const float*)d_in[9];
  float* out = (float*)d_out;

  char* w = (char*)d_ws;
  size_t off = 0;
  auto alloc = [&](size_t bytes) -> char* {
    char* p = w + off;
    off += (bytes + 511) & ~(size_t)511;
    return p;
  };
  int*      tot   = (int*)alloc((size_t)NBKT * 4);
  int*      bbase = (int*)alloc((size_t)NBKT * 4);
  int*      cbase = (int*)alloc((size_t)NBKT * 4);
  int*      offs  = (int*)alloc((size_t)(N_NODES + 1) * 4);
  int*      srcS  = (int*)alloc((size_t)N_TOT * 4);
  float*    ws2   = (float*)alloc((size_t)HID * 4);
  float*    wd2   = (float*)alloc((size_t)HID * 4);
  int*      H     = (int*)alloc((size_t)G_GROUPS * NBKT * 4);  // 1.6 MB
  _Float16* h1    = (_Float16*)alloc((size_t)N_NODES * HID * 2);  // 3.2 MB fp16
  float*    as1   = (float*)alloc((size_t)N_NODES * 4);
  float*    ad1   = (float*)alloc((size_t)N_NODES * 4);

  // union: binned (12.8MB, dead after k_bucket) vs {hr, as2, ad2}
  // (written by k_agg<true>, which runs after k_bucket — stream-ordered).
  size_t region_begin = off;
  int* binned = (int*)alloc((size_t)N_EDGES * 4);
  off = region_begin;
  _Float16* hr = (_Float16*)alloc((size_t)N_NODES * HID * 2);    // 3.2 MB fp16
  float*    as2 = (float*)alloc((size_t)N_NODES * 4);
  float*    ad2 = (float*)alloc((size_t)N_NODES * 4);

  k_g1h<<<NGEMM + G_GROUPS + 1, 512, 0, stream>>>(x, W1, as1w, ad1w, ei, H,
                                                  W2, as2w, ad2w, ws2, wd2,
                                                  h1, as1, ad1);
  k_colscan<<<NBKT, G_GROUPS, 0, stream>>>(H, tot);
  k_bscan<<<1, 256, 0, stream>>>(tot, bbase, cbase, offs);
  k_scatter<<<G_GROUPS, 256, 0, stream>>>(ei, H, bbase, binned);
  k_bucket<<<NBKT, 256, 0, stream>>>(tot, bbase, cbase, binned, offs, srcS);
  k_agg<true><<<(N_NODES + 3) / 4, 256, 0, stream>>>(offs, srcS, as1, ad1, h1,
                                                     b1, ws2, wd2, nullptr, nullptr,
                                                     hr, nullptr, as2, ad2);
  k_agg<false><<<(N_NODES + 3) / 4, 256, 0, stream>>>(offs, srcS, as2, ad2, hr,
                                                      nullptr, nullptr, nullptr,
                                                      W2, b2, nullptr, out,
                                                      nullptr, nullptr);
}